// Round 11
// baseline (85.445 us; speedup 1.0000x reference)
//
#include <hip/hip_runtime.h>

static constexpr int E = 256;
static constexpr int S = 4096;

typedef __attribute__((ext_vector_type(8))) short short8v;   // 8 bf16 (4 VGPRs)
typedef __attribute__((ext_vector_type(4))) float f32x4;     // 4 fp32 acc

static __device__ __forceinline__ unsigned short f2bf(float f) {
    union { float f; unsigned u; } v; v.f = f;
    unsigned r = v.u + 0x7fffu + ((v.u >> 16) & 1u);   // RNE
    return (unsigned short)(r >> 16);
}

static __device__ __forceinline__ f32x4 mfma16(short8v a, short8v b, f32x4 c) {
    return __builtin_amdgcn_mfma_f32_16x16x32_bf16(a, b, c, 0, 0, 0);
}

// 32x32 output tile, 1 wave. out[row,col] = sum_k A[row,k]*B[col,k] (both row-major).
static __device__ __forceinline__ void gemm_tile32(
    const unsigned short* pa0, const unsigned short* pb0,
    long sA, long sB, int K, f32x4 acc[4])
{
    const unsigned short* pa1 = pa0 + 16 * sA;
    const unsigned short* pb1 = pb0 + 16 * sB;
    #pragma unroll 4
    for (int k = 0; k < K; k += 32) {
        const short8v a0 = *(const short8v*)(pa0 + k);
        const short8v a1 = *(const short8v*)(pa1 + k);
        const short8v b0 = *(const short8v*)(pb0 + k);
        const short8v b1 = *(const short8v*)(pb1 + k);
        acc[0] = mfma16(a0, b0, acc[0]);
        acc[1] = mfma16(a0, b1, acc[1]);
        acc[2] = mfma16(a1, b0, acc[2]);
        acc[3] = mfma16(a1, b1, acc[3]);
    }
}

// ---------------------------------------------------------------------------
// y<256 : x fp32 -> XT bf16 [b][256][4096]   (no Xb — final reads x directly)
// y>=256: W* fp32 -> Wrow[wi] bf16 row-major and Wtr[wi] bf16 transposed
__global__ __launch_bounds__(256) void convert_kernel(
    const float* __restrict__ X,
    const float* __restrict__ Wq, const float* __restrict__ Wk,
    const float* __restrict__ Wv, const float* __restrict__ Wo,
    unsigned short* __restrict__ XT,
    unsigned short* __restrict__ Wrow, unsigned short* __restrict__ Wtr)
{
    __shared__ unsigned short Ls[64][66];
    const int t  = threadIdx.x;
    const int e0 = blockIdx.x * 64;
    const int lr = t >> 2;          // local row
    const int lc = (t & 3) * 16;    // local col segment
    const float* src;
    unsigned short* drow = nullptr;
    unsigned short* dtr;
    if (blockIdx.y < 256) {
        const int s0 = blockIdx.y * 64;
        src = X + (long)(s0 + lr) * E + e0 + lc;
        const int b = s0 >> 12, sl = s0 & 4095;
        dtr = XT + ((long)(b * E + e0 + lr)) * S + sl + lc;
    } else {
        const int wy = blockIdx.y - 256;
        const int wi = wy >> 2, rt = wy & 3;
        const float* W = (wi == 0) ? Wq : (wi == 1) ? Wk : (wi == 2) ? Wv : Wo;
        src  = W + (long)(rt * 64 + lr) * E + e0 + lc;
        drow = Wrow + (long)wi * 65536 + (long)(rt * 64 + lr) * E + e0 + lc;
        dtr  = Wtr  + (long)wi * 65536 + (long)(e0 + lr) * E + rt * 64 + lc;
    }
    short8v v0, v1;
    #pragma unroll
    for (int q = 0; q < 4; ++q) {
        const float4 v = *(const float4*)(src + q * 4);
        const unsigned short b0 = f2bf(v.x), b1 = f2bf(v.y), b2 = f2bf(v.z), b3 = f2bf(v.w);
        Ls[lc + q*4 + 0][lr] = b0; Ls[lc + q*4 + 1][lr] = b1;
        Ls[lc + q*4 + 2][lr] = b2; Ls[lc + q*4 + 3][lr] = b3;
        if (q < 2) { v0[q*4+0]=(short)b0; v0[q*4+1]=(short)b1; v0[q*4+2]=(short)b2; v0[q*4+3]=(short)b3; }
        else { v1[(q-2)*4+0]=(short)b0; v1[(q-2)*4+1]=(short)b1; v1[(q-2)*4+2]=(short)b2; v1[(q-2)*4+3]=(short)b3; }
    }
    if (drow) {
        *(short8v*)(drow)     = v0;
        *(short8v*)(drow + 8) = v1;
    }
    __syncthreads();
    short8v w0, w1;
    #pragma unroll
    for (int j = 0; j < 8; ++j) { w0[j] = (short)Ls[lr][lc + j]; w1[j] = (short)Ls[lr][lc + 8 + j]; }
    *(short8v*)(dtr)     = w0;
    *(short8v*)(dtr + 8) = w1;
}

// ---------------------------------------------------------------------------
// z<4 : G_b bf16 = x_b^T x_b, full K=4096. Wave = one 16x16 tile (1 f32x4 acc).
//       Block = 2x2 quad of tiles: ti = qi*2+(w>>1), tj = qj*2+(w&1). 1024 waves.
// z==4: pr plane — unit = y*8+x (0..31): P = Wq^T Wk (mode 0), Rt = Wo Wv (mode 1).
__global__ __launch_bounds__(256) void gram_pr_kernel(
    const unsigned short* __restrict__ XT, const unsigned short* __restrict__ Wrow,
    const unsigned short* __restrict__ Wtr,
    unsigned short* __restrict__ G, unsigned short* __restrict__ P,
    unsigned short* __restrict__ Rt)
{
    const int lane = threadIdx.x & 63;
    const int lr = lane & 15, lg = lane >> 4;
    if (blockIdx.z < 4) {
        const int b = blockIdx.z;
        const int w = threadIdx.x >> 6;
        const int ti = blockIdx.x * 2 + (w >> 1);    // 0..15
        const int tj = blockIdx.y * 2 + (w & 1);     // 0..15
        const unsigned short* base = XT + (long)b * E * S + lg * 8;
        const unsigned short* pa = base + (long)(ti * 16 + lr) * S;
        const unsigned short* pb = base + (long)(tj * 16 + lr) * S;
        f32x4 acc = {0.f, 0.f, 0.f, 0.f};
        #pragma unroll 8
        for (int k = 0; k < S; k += 32) {
            const short8v a  = *(const short8v*)(pa + k);
            const short8v bb = *(const short8v*)(pb + k);
            acc = mfma16(a, bb, acc);
        }
        unsigned short* out = G + ((long)b << 16);
        #pragma unroll
        for (int r = 0; r < 4; ++r)
            out[(ti * 16 + lg * 4 + r) * E + tj * 16 + lr] = f2bf(acc[r]);
    } else {
        const int unit = blockIdx.y * 8 + blockIdx.x;
        if (unit >= 32) return;
        const int mode = unit >> 4;                  // 0: P, 1: Rt
        const int w  = (unit & 15) * 4 + (threadIdx.x >> 6);
        const int ti = w >> 3, tj = w & 7;
        const unsigned short* A = (mode == 0) ? Wtr           : (Wrow + 3 * 65536);
        const unsigned short* B = (mode == 0) ? (Wtr + 65536) : (Wtr + 2 * 65536);
        f32x4 acc[4] = {};
        gemm_tile32(A + (long)(ti * 32 + lr) * E + lg * 8,
                    B + (long)(tj * 32 + lr) * E + lg * 8, E, E, E, acc);
        unsigned short* out = (mode == 0) ? P : Rt;
        #pragma unroll
        for (int q = 0; q < 4; ++q) {
            const int qr = q >> 1, qc = q & 1;
            #pragma unroll
            for (int r = 0; r < 4; ++r)
                out[(ti * 32 + qr * 16 + lg * 4 + r) * E + tj * 32 + qc * 16 + lr] = f2bf(acc[q][r]);
        }
    }
}

// ---------------------------------------------------------------------------
// grid (4 i0-bands, 4 batches, 4 g-slices), 256 threads (4 waves).
// Stage 1 (duplicated across g-slices): Tband = P[i0:i0+64,:] @ G_b -> LDS bf16.
// Stage 2: MT[b][g0:g0+64][i0:i0+64] = 1e-11 * Rt[g0:,:] @ Tband^T.
__global__ __launch_bounds__(256) void tm_kernel(
    const unsigned short* __restrict__ P, const unsigned short* __restrict__ G,
    const unsigned short* __restrict__ Rt, unsigned short* __restrict__ MT)
{
    __shared__ unsigned short Ts[64][264];
    const int b  = blockIdx.y;
    const int i0 = blockIdx.x * 64;
    const int g0 = blockIdx.z * 64;
    const int w    = threadIdx.x >> 6;
    const int lane = threadIdx.x & 63;
    const int lr = lane & 15, lg = lane >> 4;
    {   // stage 1
        const int tr = w >> 1;
        const unsigned short* pa = P + (long)(i0 + tr * 32 + lr) * E + lg * 8;
        #pragma unroll
        for (int j = 0; j < 4; ++j) {
            const int tc = (w & 1) * 4 + j;
            f32x4 acc[4] = {};
            gemm_tile32(pa, G + ((long)b << 16) + (long)(tc * 32 + lr) * E + lg * 8,
                        E, E, E, acc);
            #pragma unroll
            for (int q = 0; q < 4; ++q) {
                const int qr = q >> 1, qc = q & 1;
                #pragma unroll
                for (int r = 0; r < 4; ++r)
                    Ts[tr * 32 + qr * 16 + lg * 4 + r][tc * 32 + qc * 16 + lr] = f2bf(acc[q][r]);
            }
        }
    }
    __syncthreads();
    {   // stage 2
        const int tg = w >> 1, te = w & 1;
        f32x4 acc[4] = {};
        gemm_tile32(Rt + (long)(g0 + tg * 32 + lr) * E + lg * 8,
                    &Ts[te * 32 + lr][lg * 8], E, 264, E, acc);
        unsigned short* out = MT + ((long)b << 16);
        #pragma unroll
        for (int q = 0; q < 4; ++q) {
            const int qr = q >> 1, qc = q & 1;
            #pragma unroll
            for (int r = 0; r < 4; ++r) {
                const int g = g0 + tg * 32 + qr * 16 + lg * 4 + r;
                const int e = te * 32 + qc * 16 + lr;
                out[g * E + i0 + e] = f2bf(acc[q][r] * 1e-11f);
            }
        }
    }
}

// ---------------------------------------------------------------------------
// out = x @ M_b, reading x fp32 with in-register bf16 convert (identical RNE
// values to the old Xb). Block = 32 s-rows; 4 waves share A rows, each wave
// owns one 64-wide g-tile. grid = 512 blocks.
__global__ __launch_bounds__(256) void final_kernel(
    const float* __restrict__ X, const unsigned short* __restrict__ MT,
    float* __restrict__ Out)
{
    const int s0 = blockIdx.x * 32;
    const int b  = s0 >> 12;
    const int w  = threadIdx.x >> 6;
    const int g0 = w * 64;
    const int lane = threadIdx.x & 63;
    const int lr = lane & 15, lg = lane >> 4;
    const float* px0 = X + (long)(s0 + lr) * E + lg * 8;
    const float* px1 = px0 + 16 * E;
    const unsigned short* pb = MT + ((long)b * E + g0 + lr) * E + lg * 8;
    f32x4 acc[2][4] = {};
    #pragma unroll
    for (int k = 0; k < E; k += 32) {
        const float4 u00 = *(const float4*)(px0 + k);
        const float4 u01 = *(const float4*)(px0 + k + 4);
        const float4 u10 = *(const float4*)(px1 + k);
        const float4 u11 = *(const float4*)(px1 + k + 4);
        short8v a0, a1;
        a0[0]=(short)f2bf(u00.x); a0[1]=(short)f2bf(u00.y); a0[2]=(short)f2bf(u00.z); a0[3]=(short)f2bf(u00.w);
        a0[4]=(short)f2bf(u01.x); a0[5]=(short)f2bf(u01.y); a0[6]=(short)f2bf(u01.z); a0[7]=(short)f2bf(u01.w);
        a1[0]=(short)f2bf(u10.x); a1[1]=(short)f2bf(u10.y); a1[2]=(short)f2bf(u10.z); a1[3]=(short)f2bf(u10.w);
        a1[4]=(short)f2bf(u11.x); a1[5]=(short)f2bf(u11.y); a1[6]=(short)f2bf(u11.z); a1[7]=(short)f2bf(u11.w);
        #pragma unroll
        for (int ni = 0; ni < 4; ++ni) {
            const short8v bf = *(const short8v*)(pb + (long)ni * 16 * E + k);
            acc[0][ni] = mfma16(a0, bf, acc[0][ni]);
            acc[1][ni] = mfma16(a1, bf, acc[1][ni]);
        }
    }
    #pragma unroll
    for (int mi = 0; mi < 2; ++mi)
        #pragma unroll
        for (int r = 0; r < 4; ++r) {
            float* row = Out + (long)(s0 + mi * 16 + lg * 4 + r) * E + g0 + lr;
            #pragma unroll
            for (int ni = 0; ni < 4; ++ni) row[ni * 16] = acc[mi][ni][r];
        }
}

// ---------------------------------------------------------------------------
extern "C" void kernel_launch(void* const* d_in, const int* in_sizes, int n_in,
                              void* d_out, int out_size, void* d_ws, size_t ws_size,
                              hipStream_t stream)
{
    const float* x  = (const float*)d_in[0];
    const float* Wq = (const float*)d_in[1];
    const float* Wk = (const float*)d_in[2];
    const float* Wv = (const float*)d_in[3];
    const float* Wo = (const float*)d_in[4];
    float* out = (float*)d_out;

    char* ws = (char*)d_ws;
    unsigned short* XT   = (unsigned short*)(ws);                 //  8.39 MB
    unsigned short* Wrow = (unsigned short*)(ws + 8388608);       //  0.52 MB
    unsigned short* Wtr  = (unsigned short*)(ws + 8912896);       //  0.52 MB
    unsigned short* G    = (unsigned short*)(ws + 9437184);       //  0.52 MB
    unsigned short* P    = (unsigned short*)(ws + 9961472);       //  0.13 MB
    unsigned short* Rt   = (unsigned short*)(ws + 10092544);      //  0.13 MB
    unsigned short* MT   = (unsigned short*)(ws + 10223616);      //  0.52 MB (ends ~10.7 MB)

    convert_kernel<<<dim3(4, 272),  dim3(256), 0, stream>>>(x, Wq, Wk, Wv, Wo, XT, Wrow, Wtr);
    gram_pr_kernel<<<dim3(8, 8, 5), dim3(256), 0, stream>>>(XT, Wrow, Wtr, G, P, Rt);
    tm_kernel     <<<dim3(4, 4, 4), dim3(256), 0, stream>>>(P, G, Rt, MT);
    final_kernel  <<<dim3(512),     dim3(256), 0, stream>>>(x, MT, out);
}

// Round 12
// 75.438 us; speedup vs baseline: 1.1327x; 1.1327x over previous
//
#include <hip/hip_runtime.h>

static constexpr int E = 256;
static constexpr int S = 4096;

typedef __attribute__((ext_vector_type(8))) short short8v;   // 8 bf16 (4 VGPRs)
typedef __attribute__((ext_vector_type(4))) float f32x4;     // 4 fp32 acc

static __device__ __forceinline__ unsigned short f2bf(float f) {
    union { float f; unsigned u; } v; v.f = f;
    unsigned r = v.u + 0x7fffu + ((v.u >> 16) & 1u);   // RNE
    return (unsigned short)(r >> 16);
}

static __device__ __forceinline__ f32x4 mfma16(short8v a, short8v b, f32x4 c) {
    return __builtin_amdgcn_mfma_f32_16x16x32_bf16(a, b, c, 0, 0, 0);
}

// 32x32 output tile, 1 wave. out[row,col] = sum_k A[row,k]*B[col,k] (both row-major).
static __device__ __forceinline__ void gemm_tile32(
    const unsigned short* pa0, const unsigned short* pb0,
    long sA, long sB, int K, f32x4 acc[4])
{
    const unsigned short* pa1 = pa0 + 16 * sA;
    const unsigned short* pb1 = pb0 + 16 * sB;
    #pragma unroll 4
    for (int k = 0; k < K; k += 32) {
        const short8v a0 = *(const short8v*)(pa0 + k);
        const short8v a1 = *(const short8v*)(pa1 + k);
        const short8v b0 = *(const short8v*)(pb0 + k);
        const short8v b1 = *(const short8v*)(pb1 + k);
        acc[0] = mfma16(a0, b0, acc[0]);
        acc[1] = mfma16(a0, b1, acc[1]);
        acc[2] = mfma16(a1, b0, acc[2]);
        acc[3] = mfma16(a1, b1, acc[3]);
    }
}

// ---------------------------------------------------------------------------
// y<256 : x fp32 -> XT bf16 [b][256][4096]   (no Xb — final reads x directly)
// y>=256: W* fp32 -> Wrow[wi] bf16 row-major and Wtr[wi] bf16 transposed
__global__ __launch_bounds__(256) void convert_kernel(
    const float* __restrict__ X,
    const float* __restrict__ Wq, const float* __restrict__ Wk,
    const float* __restrict__ Wv, const float* __restrict__ Wo,
    unsigned short* __restrict__ XT,
    unsigned short* __restrict__ Wrow, unsigned short* __restrict__ Wtr)
{
    __shared__ unsigned short Ls[64][66];
    const int t  = threadIdx.x;
    const int e0 = blockIdx.x * 64;
    const int lr = t >> 2;          // local row
    const int lc = (t & 3) * 16;    // local col segment
    const float* src;
    unsigned short* drow = nullptr;
    unsigned short* dtr;
    if (blockIdx.y < 256) {
        const int s0 = blockIdx.y * 64;
        src = X + (long)(s0 + lr) * E + e0 + lc;
        const int b = s0 >> 12, sl = s0 & 4095;
        dtr = XT + ((long)(b * E + e0 + lr)) * S + sl + lc;
    } else {
        const int wy = blockIdx.y - 256;
        const int wi = wy >> 2, rt = wy & 3;
        const float* W = (wi == 0) ? Wq : (wi == 1) ? Wk : (wi == 2) ? Wv : Wo;
        src  = W + (long)(rt * 64 + lr) * E + e0 + lc;
        drow = Wrow + (long)wi * 65536 + (long)(rt * 64 + lr) * E + e0 + lc;
        dtr  = Wtr  + (long)wi * 65536 + (long)(e0 + lr) * E + rt * 64 + lc;
    }
    short8v v0, v1;
    #pragma unroll
    for (int q = 0; q < 4; ++q) {
        const float4 v = *(const float4*)(src + q * 4);
        const unsigned short b0 = f2bf(v.x), b1 = f2bf(v.y), b2 = f2bf(v.z), b3 = f2bf(v.w);
        Ls[lc + q*4 + 0][lr] = b0; Ls[lc + q*4 + 1][lr] = b1;
        Ls[lc + q*4 + 2][lr] = b2; Ls[lc + q*4 + 3][lr] = b3;
        if (q < 2) { v0[q*4+0]=(short)b0; v0[q*4+1]=(short)b1; v0[q*4+2]=(short)b2; v0[q*4+3]=(short)b3; }
        else { v1[(q-2)*4+0]=(short)b0; v1[(q-2)*4+1]=(short)b1; v1[(q-2)*4+2]=(short)b2; v1[(q-2)*4+3]=(short)b3; }
    }
    if (drow) {
        *(short8v*)(drow)     = v0;
        *(short8v*)(drow + 8) = v1;
    }
    __syncthreads();
    short8v w0, w1;
    #pragma unroll
    for (int j = 0; j < 8; ++j) { w0[j] = (short)Ls[lr][lc + j]; w1[j] = (short)Ls[lr][lc + 8 + j]; }
    *(short8v*)(dtr)     = w0;
    *(short8v*)(dtr + 8) = w1;
}

// ---------------------------------------------------------------------------
// z<4 : G_b = x_b^T x_b via in-block split-K. Block = one 32x32 tile (ti,tj),
//       512 thr; wave wv does K-chunk [wv*512, +512) with 4-acc ILP; LDS
//       cross-wave reduce; writes bf16 G directly. ti>tj blocks exit (symmetry:
//       ti<tj blocks mirror-write). Bit-identical to the old z=8+reduce path.
// z==4: pr plane — bid2 = by*8+bx < 16: mode=bid2>>3; 8 waves = 8 tiles each.
__global__ __launch_bounds__(512) void gram_pr_kernel(
    const unsigned short* __restrict__ XT, const unsigned short* __restrict__ Wrow,
    const unsigned short* __restrict__ Wtr,
    unsigned short* __restrict__ G, unsigned short* __restrict__ P,
    unsigned short* __restrict__ Rt)
{
    __shared__ float red[8][64][17];               // 34.8 KB, pad 17 -> conflict-free
    const int wv   = threadIdx.x >> 6;             // 0..7
    const int lane = threadIdx.x & 63;
    const int lr = lane & 15, lg = lane >> 4;
    if (blockIdx.z < 4) {
        const int b  = blockIdx.z;
        const int ti = blockIdx.x, tj = blockIdx.y;        // 0..7
        if (ti > tj) return;                               // symmetry
        const unsigned short* base = XT + (long)b * E * S + wv * 512 + lg * 8;
        f32x4 acc[4] = {};
        gemm_tile32(base + (long)(ti * 32 + lr) * S,
                    base + (long)(tj * 32 + lr) * S, S, S, 512, acc);
        #pragma unroll
        for (int q = 0; q < 4; ++q)
            #pragma unroll
            for (int r = 0; r < 4; ++r)
                red[wv][lane][q * 4 + r] = acc[q][r];
        __syncthreads();
        const int lane2 = threadIdx.x & 63;
        const int ib    = threadIdx.x >> 6;
        unsigned short* outg = G + ((long)b << 16);
        #pragma unroll
        for (int h = 0; h < 2; ++h) {
            const int idx = ib + h * 8;
            float s = 0.f;
            #pragma unroll
            for (int c = 0; c < 8; ++c) s += red[c][lane2][idx];
            const int q = idx >> 2, r = idx & 3;
            const int row = ti * 32 + (q >> 1) * 16 + (lane2 >> 4) * 4 + r;
            const int col = tj * 32 + (q & 1) * 16 + (lane2 & 15);
            const unsigned short v = f2bf(s);
            outg[row * E + col] = v;
            if (ti != tj) outg[col * E + row] = v;         // mirror (G symmetric)
        }
    } else {
        const int bid2 = blockIdx.y * 8 + blockIdx.x;
        if (bid2 >= 16) return;
        const int mode = bid2 >> 3;                        // 0: P, 1: Rt
        const int w  = (bid2 & 7) * 8 + wv;                // 0..63
        const int ti = w >> 3, tj = w & 7;
        const unsigned short* A = (mode == 0) ? Wtr           : (Wrow + 3 * 65536);
        const unsigned short* B = (mode == 0) ? (Wtr + 65536) : (Wtr + 2 * 65536);
        f32x4 acc[4] = {};
        gemm_tile32(A + (long)(ti * 32 + lr) * E + lg * 8,
                    B + (long)(tj * 32 + lr) * E + lg * 8, E, E, E, acc);
        unsigned short* out = (mode == 0) ? P : Rt;
        #pragma unroll
        for (int q = 0; q < 4; ++q) {
            const int qr = q >> 1, qc = q & 1;
            #pragma unroll
            for (int r = 0; r < 4; ++r)
                out[(ti * 32 + qr * 16 + lg * 4 + r) * E + tj * 32 + qc * 16 + lr] = f2bf(acc[q][r]);
        }
    }
}

// ---------------------------------------------------------------------------
// grid (4 i0-bands, 4 batches, 4 g-slices), 256 threads (4 waves).
// Stage 1 (duplicated across g-slices): Tband = P[i0:i0+64,:] @ G_b -> LDS bf16.
// Stage 2: MT[b][g0:g0+64][i0:i0+64] = 1e-11 * Rt[g0:,:] @ Tband^T.
__global__ __launch_bounds__(256) void tm_kernel(
    const unsigned short* __restrict__ P, const unsigned short* __restrict__ G,
    const unsigned short* __restrict__ Rt, unsigned short* __restrict__ MT)
{
    __shared__ unsigned short Ts[64][264];
    const int b  = blockIdx.y;
    const int i0 = blockIdx.x * 64;
    const int g0 = blockIdx.z * 64;
    const int w    = threadIdx.x >> 6;
    const int lane = threadIdx.x & 63;
    const int lr = lane & 15, lg = lane >> 4;
    {   // stage 1
        const int tr = w >> 1;
        const unsigned short* pa = P + (long)(i0 + tr * 32 + lr) * E + lg * 8;
        #pragma unroll
        for (int j = 0; j < 4; ++j) {
            const int tc = (w & 1) * 4 + j;
            f32x4 acc[4] = {};
            gemm_tile32(pa, G + ((long)b << 16) + (long)(tc * 32 + lr) * E + lg * 8,
                        E, E, E, acc);
            #pragma unroll
            for (int q = 0; q < 4; ++q) {
                const int qr = q >> 1, qc = q & 1;
                #pragma unroll
                for (int r = 0; r < 4; ++r)
                    Ts[tr * 32 + qr * 16 + lg * 4 + r][tc * 32 + qc * 16 + lr] = f2bf(acc[q][r]);
            }
        }
    }
    __syncthreads();
    {   // stage 2
        const int tg = w >> 1, te = w & 1;
        f32x4 acc[4] = {};
        gemm_tile32(Rt + (long)(g0 + tg * 32 + lr) * E + lg * 8,
                    &Ts[te * 32 + lr][lg * 8], E, 264, E, acc);
        unsigned short* out = MT + ((long)b << 16);
        #pragma unroll
        for (int q = 0; q < 4; ++q) {
            const int qr = q >> 1, qc = q & 1;
            #pragma unroll
            for (int r = 0; r < 4; ++r) {
                const int g = g0 + tg * 32 + qr * 16 + lg * 4 + r;
                const int e = te * 32 + qc * 16 + lr;
                out[g * E + i0 + e] = f2bf(acc[q][r] * 1e-11f);
            }
        }
    }
}

// ---------------------------------------------------------------------------
// out = x @ M_b, reading x fp32 with in-register bf16 convert (identical RNE
// values). Block = 32 s-rows; 4 waves share A rows, each wave owns one
// 64-wide g-tile. grid = 512 blocks.
__global__ __launch_bounds__(256) void final_kernel(
    const float* __restrict__ X, const unsigned short* __restrict__ MT,
    float* __restrict__ Out)
{
    const int s0 = blockIdx.x * 32;
    const int b  = s0 >> 12;
    const int w  = threadIdx.x >> 6;
    const int g0 = w * 64;
    const int lane = threadIdx.x & 63;
    const int lr = lane & 15, lg = lane >> 4;
    const float* px0 = X + (long)(s0 + lr) * E + lg * 8;
    const float* px1 = px0 + 16 * E;
    const unsigned short* pb = MT + ((long)b * E + g0 + lr) * E + lg * 8;
    f32x4 acc[2][4] = {};
    #pragma unroll
    for (int k = 0; k < E; k += 32) {
        const float4 u00 = *(const float4*)(px0 + k);
        const float4 u01 = *(const float4*)(px0 + k + 4);
        const float4 u10 = *(const float4*)(px1 + k);
        const float4 u11 = *(const float4*)(px1 + k + 4);
        short8v a0, a1;
        a0[0]=(short)f2bf(u00.x); a0[1]=(short)f2bf(u00.y); a0[2]=(short)f2bf(u00.z); a0[3]=(short)f2bf(u00.w);
        a0[4]=(short)f2bf(u01.x); a0[5]=(short)f2bf(u01.y); a0[6]=(short)f2bf(u01.z); a0[7]=(short)f2bf(u01.w);
        a1[0]=(short)f2bf(u10.x); a1[1]=(short)f2bf(u10.y); a1[2]=(short)f2bf(u10.z); a1[3]=(short)f2bf(u10.w);
        a1[4]=(short)f2bf(u11.x); a1[5]=(short)f2bf(u11.y); a1[6]=(short)f2bf(u11.z); a1[7]=(short)f2bf(u11.w);
        #pragma unroll
        for (int ni = 0; ni < 4; ++ni) {
            const short8v bf = *(const short8v*)(pb + (long)ni * 16 * E + k);
            acc[0][ni] = mfma16(a0, bf, acc[0][ni]);
            acc[1][ni] = mfma16(a1, bf, acc[1][ni]);
        }
    }
    #pragma unroll
    for (int mi = 0; mi < 2; ++mi)
        #pragma unroll
        for (int r = 0; r < 4; ++r) {
            float* row = Out + (long)(s0 + mi * 16 + lg * 4 + r) * E + g0 + lr;
            #pragma unroll
            for (int ni = 0; ni < 4; ++ni) row[ni * 16] = acc[mi][ni][r];
        }
}

// ---------------------------------------------------------------------------
extern "C" void kernel_launch(void* const* d_in, const int* in_sizes, int n_in,
                              void* d_out, int out_size, void* d_ws, size_t ws_size,
                              hipStream_t stream)
{
    const float* x  = (const float*)d_in[0];
    const float* Wq = (const float*)d_in[1];
    const float* Wk = (const float*)d_in[2];
    const float* Wv = (const float*)d_in[3];
    const float* Wo = (const float*)d_in[4];
    float* out = (float*)d_out;

    char* ws = (char*)d_ws;
    unsigned short* XT   = (unsigned short*)(ws);                 //  8.39 MB
    unsigned short* Wrow = (unsigned short*)(ws + 8388608);       //  0.52 MB
    unsigned short* Wtr  = (unsigned short*)(ws + 8912896);       //  0.52 MB
    unsigned short* G    = (unsigned short*)(ws + 9437184);       //  0.52 MB
    unsigned short* P    = (unsigned short*)(ws + 9961472);       //  0.13 MB
    unsigned short* Rt   = (unsigned short*)(ws + 10092544);      //  0.13 MB
    unsigned short* MT   = (unsigned short*)(ws + 10223616);      //  0.52 MB (ends ~10.7 MB)

    convert_kernel<<<dim3(4, 272),  dim3(256), 0, stream>>>(x, Wq, Wk, Wv, Wo, XT, Wrow, Wtr);
    gram_pr_kernel<<<dim3(8, 8, 5), dim3(512), 0, stream>>>(XT, Wrow, Wtr, G, P, Rt);
    tm_kernel     <<<dim3(4, 4, 4), dim3(256), 0, stream>>>(P, G, Rt, MT);
    final_kernel  <<<dim3(512),     dim3(256), 0, stream>>>(x, MT, out);
}

// Round 13
// 72.773 us; speedup vs baseline: 1.1741x; 1.0366x over previous
//
#include <hip/hip_runtime.h>

static constexpr int E = 256;
static constexpr int S = 4096;

typedef __attribute__((ext_vector_type(8))) short short8v;   // 8 bf16 (4 VGPRs)
typedef __attribute__((ext_vector_type(4))) float f32x4;     // 4 fp32 acc

static __device__ __forceinline__ unsigned short f2bf(float f) {
    union { float f; unsigned u; } v; v.f = f;
    unsigned r = v.u + 0x7fffu + ((v.u >> 16) & 1u);   // RNE
    return (unsigned short)(r >> 16);
}

static __device__ __forceinline__ f32x4 mfma16(short8v a, short8v b, f32x4 c) {
    return __builtin_amdgcn_mfma_f32_16x16x32_bf16(a, b, c, 0, 0, 0);
}

// 32x32 output tile, 1 wave. out[row,col] = sum_k A[row,k]*B[col,k] (both row-major).
static __device__ __forceinline__ void gemm_tile32(
    const unsigned short* pa0, const unsigned short* pb0,
    long sA, long sB, int K, f32x4 acc[4])
{
    const unsigned short* pa1 = pa0 + 16 * sA;
    const unsigned short* pb1 = pb0 + 16 * sB;
    #pragma unroll 4
    for (int k = 0; k < K; k += 32) {
        const short8v a0 = *(const short8v*)(pa0 + k);
        const short8v a1 = *(const short8v*)(pa1 + k);
        const short8v b0 = *(const short8v*)(pb0 + k);
        const short8v b1 = *(const short8v*)(pb1 + k);
        acc[0] = mfma16(a0, b0, acc[0]);
        acc[1] = mfma16(a0, b1, acc[1]);
        acc[2] = mfma16(a1, b0, acc[2]);
        acc[3] = mfma16(a1, b1, acc[3]);
    }
}

// ---------------------------------------------------------------------------
// K1: P = Wq^T Wk (blocks 0..15), Rt = Wo Wv (blocks 16..31). 256 thr.
// Per block: stage two 64x256 bf16 panels in LDS (transposing as needed from
// raw fp32 W), then 4 waves compute the 64x64 output tile.
__global__ __launch_bounds__(256) void pr_kernel(
    const float* __restrict__ Wq, const float* __restrict__ Wk,
    const float* __restrict__ Wv, const float* __restrict__ Wo,
    unsigned short* __restrict__ P, unsigned short* __restrict__ Rt)
{
    __shared__ unsigned short PA[64][264];
    __shared__ unsigned short PB[64][264];
    const int bid  = blockIdx.x;
    const int mode = bid >> 4;                 // 0: P, 1: Rt
    const int tile = bid & 15;
    const int I0 = (tile >> 2) * 64, J0 = (tile & 3) * 64;
    const int t = threadIdx.x;
    {   // PB: always transposed: PB[j][g] = (mode? Wv : Wk)[g][J0+j]; thread t = row g
        const float* row = (mode ? Wv : Wk) + (long)t * E + J0;
        #pragma unroll
        for (int q = 0; q < 16; ++q) {
            const float4 v = ((const float4*)row)[q];
            PB[q*4+0][t] = f2bf(v.x); PB[q*4+1][t] = f2bf(v.y);
            PB[q*4+2][t] = f2bf(v.z); PB[q*4+3][t] = f2bf(v.w);
        }
    }
    if (mode == 0) {                           // PA[i][g] = Wq[g][I0+i] (transpose)
        const float* row = Wq + (long)t * E + I0;
        #pragma unroll
        for (int q = 0; q < 16; ++q) {
            const float4 v = ((const float4*)row)[q];
            PA[q*4+0][t] = f2bf(v.x); PA[q*4+1][t] = f2bf(v.y);
            PA[q*4+2][t] = f2bf(v.z); PA[q*4+3][t] = f2bf(v.w);
        }
    } else {                                   // PA[r][f] = Wo[I0+r][f] (row-major)
        const int r = t >> 2, seg = (t & 3) * 64;
        const float* row = Wo + (long)(I0 + r) * E + seg;
        #pragma unroll
        for (int q = 0; q < 16; ++q) {
            const float4 v = ((const float4*)row)[q];
            PA[r][seg + q*4 + 0] = f2bf(v.x); PA[r][seg + q*4 + 1] = f2bf(v.y);
            PA[r][seg + q*4 + 2] = f2bf(v.z); PA[r][seg + q*4 + 3] = f2bf(v.w);
        }
    }
    __syncthreads();
    const int w = t >> 6, lane = t & 63, lr = lane & 15, lg = lane >> 4;
    f32x4 acc[4] = {};
    gemm_tile32(&PA[(w >> 1) * 32 + lr][lg * 8],
                &PB[(w & 1) * 32 + lr][lg * 8], 264, 264, 256, acc);
    unsigned short* out = mode ? Rt : P;
    #pragma unroll
    for (int q = 0; q < 4; ++q) {
        const int qr = q >> 1, qc = q & 1;
        #pragma unroll
        for (int r = 0; r < 4; ++r)
            out[(I0 + (w >> 1) * 32 + qr * 16 + lg * 4 + r) * E
                + J0 + (w & 1) * 32 + qc * 16 + lr] = f2bf(acc[q][r]);
    }
}

// ---------------------------------------------------------------------------
// K2: Y = Xb @ P^T, Z = Xb @ R~  (Y[s,e']=sum_e X[s,e]P[e',e]; Z[s,g]=sum_e X[s,e]Rt[g,e])
// 512 blocks x 512 thr. Block = 32 s-rows. Stage A rows (fp32->bf16) in LDS once;
// 8 waves: w<4 -> Y cols w*64.., w>=4 -> Z cols (w-4)*64.. . Epilogue: LDS
// transpose, write YT[b][e'][s], ZT[b][g][s].
__global__ __launch_bounds__(512) void yz_kernel(
    const float* __restrict__ X, const unsigned short* __restrict__ P,
    const unsigned short* __restrict__ Rt,
    unsigned short* __restrict__ YT, unsigned short* __restrict__ ZT)
{
    __shared__ unsigned short lds[512 * 40];   // 40 KB union: Xs[32][264] / Tt[512][40]
    unsigned short (*Xs)[264] = (unsigned short (*)[264])lds;
    unsigned short (*Tt)[40]  = (unsigned short (*)[40])lds;
    const int sg = blockIdx.x * 32;
    const int b  = sg >> 12;
    const int t  = threadIdx.x;
    {   // stage 32 x-rows as bf16
        const int r = t >> 4, c = (t & 15) * 16;
        const float* src = X + (long)(sg + r) * E + c;
        short8v u0, u1;
        #pragma unroll
        for (int q = 0; q < 4; ++q) {
            const float4 v = ((const float4*)src)[q];
            const unsigned short b0 = f2bf(v.x), b1 = f2bf(v.y), b2 = f2bf(v.z), b3 = f2bf(v.w);
            if (q < 2) { u0[q*4+0]=(short)b0; u0[q*4+1]=(short)b1; u0[q*4+2]=(short)b2; u0[q*4+3]=(short)b3; }
            else { u1[(q-2)*4+0]=(short)b0; u1[(q-2)*4+1]=(short)b1; u1[(q-2)*4+2]=(short)b2; u1[(q-2)*4+3]=(short)b3; }
        }
        *(short8v*)&Xs[r][c]     = u0;
        *(short8v*)&Xs[r][c + 8] = u1;
    }
    __syncthreads();
    const int w = t >> 6, lane = t & 63, lr = lane & 15, lg = lane >> 4;
    const unsigned short* Bmat = (w < 4) ? P : Rt;
    const int cb = (w & 3) * 64;
    const unsigned short* pb  = Bmat + (long)(cb + lr) * E + lg * 8;
    const unsigned short* pa0 = &Xs[lr][lg * 8];
    const unsigned short* pa1 = &Xs[16 + lr][lg * 8];
    f32x4 acc[2][4] = {};
    #pragma unroll
    for (int k = 0; k < E; k += 32) {
        const short8v a0 = *(const short8v*)(pa0 + k);
        const short8v a1 = *(const short8v*)(pa1 + k);
        #pragma unroll
        for (int ni = 0; ni < 4; ++ni) {
            const short8v bf = *(const short8v*)(pb + (long)ni * 16 * E + k);
            acc[0][ni] = mfma16(a0, bf, acc[0][ni]);
            acc[1][ni] = mfma16(a1, bf, acc[1][ni]);
        }
    }
    __syncthreads();                           // Xs dead; reuse as Tt
    const int crow = (w < 4 ? cb : 256 + cb);
    #pragma unroll
    for (int mi = 0; mi < 2; ++mi)
        #pragma unroll
        for (int ni = 0; ni < 4; ++ni)
            #pragma unroll
            for (int r = 0; r < 4; ++r)
                Tt[crow + ni * 16 + lr][mi * 16 + lg * 4 + r] = f2bf(acc[mi][ni][r]);
    __syncthreads();
    {   // write-out: thread t owns transposed row c = t (Y: 0..255, Z: 256..511)
        unsigned short* dst = (t < 256)
            ? (YT + ((long)(b * E + t)) * S + (sg & 4095))
            : (ZT + ((long)(b * E + (t - 256))) * S + (sg & 4095));
        #pragma unroll
        for (int q = 0; q < 4; ++q)
            *(short8v*)(dst + q * 8) = *(const short8v*)&Tt[t][q * 8];
    }
}

// ---------------------------------------------------------------------------
// K3: MT[b][g][e] = 1e-11 * sum_s ZT[b][g][s] * YT[b][e][s].
// grid (8,8,4) = 256 blocks x 512 thr; 8 waves split K=4096 into 512-chunks,
// LDS cross-wave reduce (structure identical to R12's validated gram).
__global__ __launch_bounds__(512) void mt_kernel(
    const unsigned short* __restrict__ ZT, const unsigned short* __restrict__ YT,
    unsigned short* __restrict__ MT)
{
    __shared__ float red[8][64][17];
    const int wv   = threadIdx.x >> 6;
    const int lane = threadIdx.x & 63;
    const int lr = lane & 15, lg = lane >> 4;
    const int ti = blockIdx.x, tj = blockIdx.y, b = blockIdx.z;
    const unsigned short* Abase = ZT + (long)b * E * S + wv * 512 + lg * 8;
    const unsigned short* Bbase = YT + (long)b * E * S + wv * 512 + lg * 8;
    f32x4 acc[4] = {};
    gemm_tile32(Abase + (long)(ti * 32 + lr) * S,
                Bbase + (long)(tj * 32 + lr) * S, S, S, 512, acc);
    #pragma unroll
    for (int q = 0; q < 4; ++q)
        #pragma unroll
        for (int r = 0; r < 4; ++r)
            red[wv][lane][q * 4 + r] = acc[q][r];
    __syncthreads();
    const int lane2 = threadIdx.x & 63;
    const int ib    = threadIdx.x >> 6;
    unsigned short* outg = MT + ((long)b << 16);
    #pragma unroll
    for (int h = 0; h < 2; ++h) {
        const int idx = ib + h * 8;
        float s = 0.f;
        #pragma unroll
        for (int c = 0; c < 8; ++c) s += red[c][lane2][idx];
        const int q = idx >> 2, r = idx & 3;
        const int row = ti * 32 + (q >> 1) * 16 + (lane2 >> 4) * 4 + r;   // g
        const int col = tj * 32 + (q & 1) * 16 + (lane2 & 15);            // e
        outg[row * E + col] = f2bf(s * 1e-11f);
    }
}

// ---------------------------------------------------------------------------
// K4: out = x @ M_b, reading x fp32 with in-register bf16 convert.
// Block = 32 s-rows; 4 waves share A rows, each wave owns one 64-wide g-tile.
__global__ __launch_bounds__(256) void final_kernel(
    const float* __restrict__ X, const unsigned short* __restrict__ MT,
    float* __restrict__ Out)
{
    const int s0 = blockIdx.x * 32;
    const int b  = s0 >> 12;
    const int w  = threadIdx.x >> 6;
    const int g0 = w * 64;
    const int lane = threadIdx.x & 63;
    const int lr = lane & 15, lg = lane >> 4;
    const float* px0 = X + (long)(s0 + lr) * E + lg * 8;
    const float* px1 = px0 + 16 * E;
    const unsigned short* pb = MT + ((long)b * E + g0 + lr) * E + lg * 8;
    f32x4 acc[2][4] = {};
    #pragma unroll
    for (int k = 0; k < E; k += 32) {
        const float4 u00 = *(const float4*)(px0 + k);
        const float4 u01 = *(const float4*)(px0 + k + 4);
        const float4 u10 = *(const float4*)(px1 + k);
        const float4 u11 = *(const float4*)(px1 + k + 4);
        short8v a0, a1;
        a0[0]=(short)f2bf(u00.x); a0[1]=(short)f2bf(u00.y); a0[2]=(short)f2bf(u00.z); a0[3]=(short)f2bf(u00.w);
        a0[4]=(short)f2bf(u01.x); a0[5]=(short)f2bf(u01.y); a0[6]=(short)f2bf(u01.z); a0[7]=(short)f2bf(u01.w);
        a1[0]=(short)f2bf(u10.x); a1[1]=(short)f2bf(u10.y); a1[2]=(short)f2bf(u10.z); a1[3]=(short)f2bf(u10.w);
        a1[4]=(short)f2bf(u11.x); a1[5]=(short)f2bf(u11.y); a1[6]=(short)f2bf(u11.z); a1[7]=(short)f2bf(u11.w);
        #pragma unroll
        for (int ni = 0; ni < 4; ++ni) {
            const short8v bf = *(const short8v*)(pb + (long)ni * 16 * E + k);
            acc[0][ni] = mfma16(a0, bf, acc[0][ni]);
            acc[1][ni] = mfma16(a1, bf, acc[1][ni]);
        }
    }
    #pragma unroll
    for (int mi = 0; mi < 2; ++mi)
        #pragma unroll
        for (int r = 0; r < 4; ++r) {
            float* row = Out + (long)(s0 + mi * 16 + lg * 4 + r) * E + g0 + lr;
            #pragma unroll
            for (int ni = 0; ni < 4; ++ni) row[ni * 16] = acc[mi][ni][r];
        }
}

// ---------------------------------------------------------------------------
extern "C" void kernel_launch(void* const* d_in, const int* in_sizes, int n_in,
                              void* d_out, int out_size, void* d_ws, size_t ws_size,
                              hipStream_t stream)
{
    const float* x  = (const float*)d_in[0];
    const float* Wq = (const float*)d_in[1];
    const float* Wk = (const float*)d_in[2];
    const float* Wv = (const float*)d_in[3];
    const float* Wo = (const float*)d_in[4];
    float* out = (float*)d_out;

    char* ws = (char*)d_ws;
    unsigned short* YT = (unsigned short*)(ws);                   //  8.39 MB
    unsigned short* ZT = (unsigned short*)(ws + 8388608);         //  8.39 MB
    unsigned short* P  = (unsigned short*)(ws + 16777216);        //  0.13 MB
    unsigned short* Rt = (unsigned short*)(ws + 16908288);        //  0.13 MB
    unsigned short* MT = (unsigned short*)(ws + 17039360);        //  0.52 MB (ends ~17.6 MB)

    pr_kernel   <<<dim3(32),      dim3(256), 0, stream>>>(Wq, Wk, Wv, Wo, P, Rt);
    yz_kernel   <<<dim3(512),     dim3(512), 0, stream>>>(x, P, Rt, YT, ZT);
    mt_kernel   <<<dim3(8, 8, 4), dim3(512), 0, stream>>>(ZT, YT, MT);
    final_kernel<<<dim3(512),     dim3(256), 0, stream>>>(x, MT, out);
}

// Round 14
// 67.826 us; speedup vs baseline: 1.2598x; 1.0729x over previous
//
#include <hip/hip_runtime.h>

static constexpr int E = 256;
static constexpr int S = 4096;

typedef __attribute__((ext_vector_type(8))) short short8v;   // 8 bf16 (4 VGPRs)
typedef __attribute__((ext_vector_type(4))) float f32x4;     // 4 fp32 acc

static __device__ __forceinline__ unsigned short f2bf(float f) {
    union { float f; unsigned u; } v; v.f = f;
    unsigned r = v.u + 0x7fffu + ((v.u >> 16) & 1u);   // RNE
    return (unsigned short)(r >> 16);
}

static __device__ __forceinline__ f32x4 mfma16(short8v a, short8v b, f32x4 c) {
    return __builtin_amdgcn_mfma_f32_16x16x32_bf16(a, b, c, 0, 0, 0);
}

// 32x32 output tile, 1 wave. out[row,col] = sum_k A[row,k]*B[col,k] (both row-major).
static __device__ __forceinline__ void gemm_tile32(
    const unsigned short* pa0, const unsigned short* pb0,
    long sA, long sB, int K, f32x4 acc[4])
{
    const unsigned short* pa1 = pa0 + 16 * sA;
    const unsigned short* pb1 = pb0 + 16 * sB;
    #pragma unroll 4
    for (int k = 0; k < K; k += 32) {
        const short8v a0 = *(const short8v*)(pa0 + k);
        const short8v a1 = *(const short8v*)(pa1 + k);
        const short8v b0 = *(const short8v*)(pb0 + k);
        const short8v b1 = *(const short8v*)(pb1 + k);
        acc[0] = mfma16(a0, b0, acc[0]);
        acc[1] = mfma16(a0, b1, acc[1]);
        acc[2] = mfma16(a1, b0, acc[2]);
        acc[3] = mfma16(a1, b1, acc[3]);
    }
}

// ---------------------------------------------------------------------------
// K1: P = Wq^T Wk (blocks 0..15), Rt = Wo Wv (blocks 16..31). 256 thr.
__global__ __launch_bounds__(256) void pr_kernel(
    const float* __restrict__ Wq, const float* __restrict__ Wk,
    const float* __restrict__ Wv, const float* __restrict__ Wo,
    unsigned short* __restrict__ P, unsigned short* __restrict__ Rt)
{
    __shared__ unsigned short PA[64][264];
    __shared__ unsigned short PB[64][264];
    const int bid  = blockIdx.x;
    const int mode = bid >> 4;                 // 0: P, 1: Rt
    const int tile = bid & 15;
    const int I0 = (tile >> 2) * 64, J0 = (tile & 3) * 64;
    const int t = threadIdx.x;
    {   // PB always transposed: PB[j][g] = (mode? Wv : Wk)[g][J0+j]
        const float* row = (mode ? Wv : Wk) + (long)t * E + J0;
        #pragma unroll
        for (int q = 0; q < 16; ++q) {
            const float4 v = ((const float4*)row)[q];
            PB[q*4+0][t] = f2bf(v.x); PB[q*4+1][t] = f2bf(v.y);
            PB[q*4+2][t] = f2bf(v.z); PB[q*4+3][t] = f2bf(v.w);
        }
    }
    if (mode == 0) {                           // PA[i][g] = Wq[g][I0+i]
        const float* row = Wq + (long)t * E + I0;
        #pragma unroll
        for (int q = 0; q < 16; ++q) {
            const float4 v = ((const float4*)row)[q];
            PA[q*4+0][t] = f2bf(v.x); PA[q*4+1][t] = f2bf(v.y);
            PA[q*4+2][t] = f2bf(v.z); PA[q*4+3][t] = f2bf(v.w);
        }
    } else {                                   // PA[r][f] = Wo[I0+r][f]
        const int r = t >> 2, seg = (t & 3) * 64;
        const float* row = Wo + (long)(I0 + r) * E + seg;
        #pragma unroll
        for (int q = 0; q < 16; ++q) {
            const float4 v = ((const float4*)row)[q];
            PA[r][seg + q*4 + 0] = f2bf(v.x); PA[r][seg + q*4 + 1] = f2bf(v.y);
            PA[r][seg + q*4 + 2] = f2bf(v.z); PA[r][seg + q*4 + 3] = f2bf(v.w);
        }
    }
    __syncthreads();
    const int w = t >> 6, lane = t & 63, lr = lane & 15, lg = lane >> 4;
    f32x4 acc[4] = {};
    gemm_tile32(&PA[(w >> 1) * 32 + lr][lg * 8],
                &PB[(w & 1) * 32 + lr][lg * 8], 264, 264, 256, acc);
    unsigned short* out = mode ? Rt : P;
    #pragma unroll
    for (int q = 0; q < 4; ++q) {
        const int qr = q >> 1, qc = q & 1;
        #pragma unroll
        for (int r = 0; r < 4; ++r)
            out[(I0 + (w >> 1) * 32 + qr * 16 + lg * 4 + r) * E
                + J0 + (w & 1) * 32 + qc * 16 + lr] = f2bf(acc[q][r]);
    }
}

// ---------------------------------------------------------------------------
// K2: Y = Xb @ P^T, Z = Xb @ R~. Also spills the staged bf16 x-panel to Xb
// (final reuses it — bit-identical to converting in final).
// 512 blocks x 512 thr. Epilogue: LDS transpose -> YT[b][e'][s], ZT[b][g][s].
__global__ __launch_bounds__(512) void yz_kernel(
    const float* __restrict__ X, const unsigned short* __restrict__ P,
    const unsigned short* __restrict__ Rt,
    unsigned short* __restrict__ YT, unsigned short* __restrict__ ZT,
    unsigned short* __restrict__ Xb)
{
    __shared__ unsigned short lds[512 * 40];   // 40 KB union: Xs[32][264] / Tt[512][40]
    unsigned short (*Xs)[264] = (unsigned short (*)[264])lds;
    unsigned short (*Tt)[40]  = (unsigned short (*)[40])lds;
    const int sg = blockIdx.x * 32;
    const int b  = sg >> 12;
    const int t  = threadIdx.x;
    {   // stage 32 x-rows as bf16; also write to global Xb
        const int r = t >> 4, c = (t & 15) * 16;
        const float* src = X + (long)(sg + r) * E + c;
        short8v u0, u1;
        #pragma unroll
        for (int q = 0; q < 4; ++q) {
            const float4 v = ((const float4*)src)[q];
            const unsigned short b0 = f2bf(v.x), b1 = f2bf(v.y), b2 = f2bf(v.z), b3 = f2bf(v.w);
            if (q < 2) { u0[q*4+0]=(short)b0; u0[q*4+1]=(short)b1; u0[q*4+2]=(short)b2; u0[q*4+3]=(short)b3; }
            else { u1[(q-2)*4+0]=(short)b0; u1[(q-2)*4+1]=(short)b1; u1[(q-2)*4+2]=(short)b2; u1[(q-2)*4+3]=(short)b3; }
        }
        *(short8v*)&Xs[r][c]     = u0;
        *(short8v*)&Xs[r][c + 8] = u1;
        unsigned short* xb = Xb + (long)(sg + r) * E + c;
        *(short8v*)(xb)     = u0;
        *(short8v*)(xb + 8) = u1;
    }
    __syncthreads();
    const int w = t >> 6, lane = t & 63, lr = lane & 15, lg = lane >> 4;
    const unsigned short* Bmat = (w < 4) ? P : Rt;
    const int cb = (w & 3) * 64;
    const unsigned short* pb  = Bmat + (long)(cb + lr) * E + lg * 8;
    const unsigned short* pa0 = &Xs[lr][lg * 8];
    const unsigned short* pa1 = &Xs[16 + lr][lg * 8];
    f32x4 acc[2][4] = {};
    #pragma unroll
    for (int k = 0; k < E; k += 32) {
        const short8v a0 = *(const short8v*)(pa0 + k);
        const short8v a1 = *(const short8v*)(pa1 + k);
        #pragma unroll
        for (int ni = 0; ni < 4; ++ni) {
            const short8v bf = *(const short8v*)(pb + (long)ni * 16 * E + k);
            acc[0][ni] = mfma16(a0, bf, acc[0][ni]);
            acc[1][ni] = mfma16(a1, bf, acc[1][ni]);
        }
    }
    __syncthreads();                           // Xs dead; reuse as Tt
    const int crow = (w < 4 ? cb : 256 + cb);
    #pragma unroll
    for (int mi = 0; mi < 2; ++mi)
        #pragma unroll
        for (int ni = 0; ni < 4; ++ni)
            #pragma unroll
            for (int r = 0; r < 4; ++r)
                Tt[crow + ni * 16 + lr][mi * 16 + lg * 4 + r] = f2bf(acc[mi][ni][r]);
    __syncthreads();
    {   // write-out: thread t owns transposed row c = t (Y: 0..255, Z: 256..511)
        unsigned short* dst = (t < 256)
            ? (YT + ((long)(b * E + t)) * S + (sg & 4095))
            : (ZT + ((long)(b * E + (t - 256))) * S + (sg & 4095));
        #pragma unroll
        for (int q = 0; q < 4; ++q)
            *(short8v*)(dst + q * 8) = *(const short8v*)&Tt[t][q * 8];
    }
}

// ---------------------------------------------------------------------------
// K3: MT[b][g][e] = 1e-11 * sum_s ZT[b][g][s] * YT[b][e][s].
// 256 blocks x 512 thr; 8-way split-K + LDS reduce. XCD-chunk swizzle:
// tile = (bid%8)*32 + bid/8 -> each XCD works one batch's contiguous chunk
// (ZT 2MB + YT 1MB = 3MB working set, fits 4MB per-XCD L2).
__global__ __launch_bounds__(512) void mt_kernel(
    const unsigned short* __restrict__ ZT, const unsigned short* __restrict__ YT,
    unsigned short* __restrict__ MT)
{
    __shared__ float red[8][64][17];
    const int tile = (blockIdx.x & 7) * 32 + (blockIdx.x >> 3);   // bijective, 256
    const int b  = tile >> 6;
    const int tj = (tile >> 3) & 7;
    const int ti = tile & 7;
    const int wv   = threadIdx.x >> 6;
    const int lane = threadIdx.x & 63;
    const int lr = lane & 15, lg = lane >> 4;
    const unsigned short* Abase = ZT + (long)b * E * S + wv * 512 + lg * 8;
    const unsigned short* Bbase = YT + (long)b * E * S + wv * 512 + lg * 8;
    f32x4 acc[4] = {};
    gemm_tile32(Abase + (long)(ti * 32 + lr) * S,
                Bbase + (long)(tj * 32 + lr) * S, S, S, 512, acc);
    #pragma unroll
    for (int q = 0; q < 4; ++q)
        #pragma unroll
        for (int r = 0; r < 4; ++r)
            red[wv][lane][q * 4 + r] = acc[q][r];
    __syncthreads();
    const int lane2 = threadIdx.x & 63;
    const int ib    = threadIdx.x >> 6;
    unsigned short* outg = MT + ((long)b << 16);
    #pragma unroll
    for (int h = 0; h < 2; ++h) {
        const int idx = ib + h * 8;
        float s = 0.f;
        #pragma unroll
        for (int c = 0; c < 8; ++c) s += red[c][lane2][idx];
        const int q = idx >> 2, r = idx & 3;
        const int row = ti * 32 + (q >> 1) * 16 + (lane2 >> 4) * 4 + r;   // g
        const int col = tj * 32 + (q & 1) * 16 + (lane2 & 15);            // e
        outg[row * E + col] = f2bf(s * 1e-11f);
    }
}

// ---------------------------------------------------------------------------
// K4: out = Xb @ M_b (bf16 Xb written by yz — zero conversions here).
// Block = 32 s-rows; 4 waves share A rows, each wave owns one 64-wide g-tile.
__global__ __launch_bounds__(256) void final_kernel(
    const unsigned short* __restrict__ Xb, const unsigned short* __restrict__ MT,
    float* __restrict__ Out)
{
    const int s0 = blockIdx.x * 32;
    const int b  = s0 >> 12;
    const int w  = threadIdx.x >> 6;
    const int g0 = w * 64;
    const int lane = threadIdx.x & 63;
    const int lr = lane & 15, lg = lane >> 4;
    const unsigned short* pa0 = Xb + (long)(s0 + lr) * E + lg * 8;
    const unsigned short* pa1 = pa0 + 16 * E;
    const unsigned short* pb  = MT + ((long)b * E + g0 + lr) * E + lg * 8;
    f32x4 acc[2][4] = {};
    #pragma unroll
    for (int k = 0; k < E; k += 32) {
        const short8v a0 = *(const short8v*)(pa0 + k);
        const short8v a1 = *(const short8v*)(pa1 + k);
        #pragma unroll
        for (int ni = 0; ni < 4; ++ni) {
            const short8v bf = *(const short8v*)(pb + (long)ni * 16 * E + k);
            acc[0][ni] = mfma16(a0, bf, acc[0][ni]);
            acc[1][ni] = mfma16(a1, bf, acc[1][ni]);
        }
    }
    #pragma unroll
    for (int mi = 0; mi < 2; ++mi)
        #pragma unroll
        for (int r = 0; r < 4; ++r) {
            float* row = Out + (long)(s0 + mi * 16 + lg * 4 + r) * E + g0 + lr;
            #pragma unroll
            for (int ni = 0; ni < 4; ++ni) row[ni * 16] = acc[mi][ni][r];
        }
}

// ---------------------------------------------------------------------------
extern "C" void kernel_launch(void* const* d_in, const int* in_sizes, int n_in,
                              void* d_out, int out_size, void* d_ws, size_t ws_size,
                              hipStream_t stream)
{
    const float* x  = (const float*)d_in[0];
    const float* Wq = (const float*)d_in[1];
    const float* Wk = (const float*)d_in[2];
    const float* Wv = (const float*)d_in[3];
    const float* Wo = (const float*)d_in[4];
    float* out = (float*)d_out;

    char* ws = (char*)d_ws;
    unsigned short* YT = (unsigned short*)(ws);                   //  8.39 MB
    unsigned short* ZT = (unsigned short*)(ws + 8388608);         //  8.39 MB
    unsigned short* Xb = (unsigned short*)(ws + 16777216);        //  8.39 MB
    unsigned short* P  = (unsigned short*)(ws + 25165824);        //  0.13 MB
    unsigned short* Rt = (unsigned short*)(ws + 25296896);        //  0.13 MB
    unsigned short* MT = (unsigned short*)(ws + 25427968);        //  0.52 MB (ends ~26 MB)

    pr_kernel   <<<dim3(32),  dim3(256), 0, stream>>>(Wq, Wk, Wv, Wo, P, Rt);
    yz_kernel   <<<dim3(512), dim3(512), 0, stream>>>(x, P, Rt, YT, ZT, Xb);
    mt_kernel   <<<dim3(256), dim3(512), 0, stream>>>(ZT, YT, MT);
    final_kernel<<<dim3(512), dim3(256), 0, stream>>>(Xb, MT, out);
}

// Round 15
// 64.974 us; speedup vs baseline: 1.3151x; 1.0439x over previous
//
#include <hip/hip_runtime.h>

static constexpr int E = 256;
static constexpr int S = 4096;

typedef __attribute__((ext_vector_type(8))) short short8v;   // 8 bf16 (4 VGPRs)
typedef __attribute__((ext_vector_type(4))) float f32x4;     // 4 fp32 acc

static __device__ __forceinline__ unsigned short f2bf(float f) {
    union { float f; unsigned u; } v; v.f = f;
    unsigned r = v.u + 0x7fffu + ((v.u >> 16) & 1u);   // RNE
    return (unsigned short)(r >> 16);
}

static __device__ __forceinline__ f32x4 mfma16(short8v a, short8v b, f32x4 c) {
    return __builtin_amdgcn_mfma_f32_16x16x32_bf16(a, b, c, 0, 0, 0);
}

// 32x32 output tile, 1 wave. out[row,col] = sum_k A[row,k]*B[col,k] (both row-major).
static __device__ __forceinline__ void gemm_tile32(
    const unsigned short* pa0, const unsigned short* pb0,
    long sA, long sB, int K, f32x4 acc[4])
{
    const unsigned short* pa1 = pa0 + 16 * sA;
    const unsigned short* pb1 = pb0 + 16 * sB;
    #pragma unroll 4
    for (int k = 0; k < K; k += 32) {
        const short8v a0 = *(const short8v*)(pa0 + k);
        const short8v a1 = *(const short8v*)(pa1 + k);
        const short8v b0 = *(const short8v*)(pb0 + k);
        const short8v b1 = *(const short8v*)(pb1 + k);
        acc[0] = mfma16(a0, b0, acc[0]);
        acc[1] = mfma16(a0, b1, acc[1]);
        acc[2] = mfma16(a1, b0, acc[2]);
        acc[3] = mfma16(a1, b1, acc[3]);
    }
}

// ---------------------------------------------------------------------------
// K1: P = Wq^T Wk (blocks 0..15), Rt = Wo Wv (blocks 16..31). 256 thr.
__global__ __launch_bounds__(256) void pr_kernel(
    const float* __restrict__ Wq, const float* __restrict__ Wk,
    const float* __restrict__ Wv, const float* __restrict__ Wo,
    unsigned short* __restrict__ P, unsigned short* __restrict__ Rt)
{
    __shared__ unsigned short PA[64][264];
    __shared__ unsigned short PB[64][264];
    const int bid  = blockIdx.x;
    const int mode = bid >> 4;                 // 0: P, 1: Rt
    const int tile = bid & 15;
    const int I0 = (tile >> 2) * 64, J0 = (tile & 3) * 64;
    const int t = threadIdx.x;
    {   // PB always transposed: PB[j][g] = (mode? Wv : Wk)[g][J0+j]
        const float* row = (mode ? Wv : Wk) + (long)t * E + J0;
        #pragma unroll
        for (int q = 0; q < 16; ++q) {
            const float4 v = ((const float4*)row)[q];
            PB[q*4+0][t] = f2bf(v.x); PB[q*4+1][t] = f2bf(v.y);
            PB[q*4+2][t] = f2bf(v.z); PB[q*4+3][t] = f2bf(v.w);
        }
    }
    if (mode == 0) {                           // PA[i][g] = Wq[g][I0+i]
        const float* row = Wq + (long)t * E + I0;
        #pragma unroll
        for (int q = 0; q < 16; ++q) {
            const float4 v = ((const float4*)row)[q];
            PA[q*4+0][t] = f2bf(v.x); PA[q*4+1][t] = f2bf(v.y);
            PA[q*4+2][t] = f2bf(v.z); PA[q*4+3][t] = f2bf(v.w);
        }
    } else {                                   // PA[r][f] = Wo[I0+r][f]
        const int r = t >> 2, seg = (t & 3) * 64;
        const float* row = Wo + (long)(I0 + r) * E + seg;
        #pragma unroll
        for (int q = 0; q < 16; ++q) {
            const float4 v = ((const float4*)row)[q];
            PA[r][seg + q*4 + 0] = f2bf(v.x); PA[r][seg + q*4 + 1] = f2bf(v.y);
            PA[r][seg + q*4 + 2] = f2bf(v.z); PA[r][seg + q*4 + 3] = f2bf(v.w);
        }
    }
    __syncthreads();
    const int w = t >> 6, lane = t & 63, lr = lane & 15, lg = lane >> 4;
    f32x4 acc[4] = {};
    gemm_tile32(&PA[(w >> 1) * 32 + lr][lg * 8],
                &PB[(w & 1) * 32 + lr][lg * 8], 264, 264, 256, acc);
    unsigned short* out = mode ? Rt : P;
    #pragma unroll
    for (int q = 0; q < 4; ++q) {
        const int qr = q >> 1, qc = q & 1;
        #pragma unroll
        for (int r = 0; r < 4; ++r)
            out[(I0 + (w >> 1) * 32 + qr * 16 + lg * 4 + r) * E
                + J0 + (w & 1) * 32 + qc * 16 + lr] = f2bf(acc[q][r]);
    }
}

// ---------------------------------------------------------------------------
// K2: Y = Xb @ P^T, Z = Xb @ R~. 256 blocks x 512 thr, 64 s-rows per block.
// Stage 64 x-rows fp32->bf16 in LDS (+spill to Xb); 8 waves: w<4 -> Y cols
// w*64.., w>=4 -> Z cols. Each wave: 64x64 output (acc[4][4]).
// Epilogue: LDS transpose -> YT[b][e'][s], ZT[b][g][s].
__global__ __launch_bounds__(512) void yz_kernel(
    const float* __restrict__ X, const unsigned short* __restrict__ P,
    const unsigned short* __restrict__ Rt,
    unsigned short* __restrict__ YT, unsigned short* __restrict__ ZT,
    unsigned short* __restrict__ Xb)
{
    __shared__ unsigned short lds[512 * 72];   // 73.7 KB union: Xs[64][264] / Tt[512][72]
    unsigned short (*Xs)[264] = (unsigned short (*)[264])lds;
    unsigned short (*Tt)[72]  = (unsigned short (*)[72])lds;
    const int sg = blockIdx.x * 64;
    const int b  = sg >> 12;
    const int t  = threadIdx.x;
    {   // stage 64 x-rows as bf16 (8 thr/row, 32 floats each); also spill to Xb
        const int r = t >> 3, c = (t & 7) * 32;
        const float* src = X + (long)(sg + r) * E + c;
        short8v u[4];
        #pragma unroll
        for (int q = 0; q < 8; ++q) {
            const float4 v = ((const float4*)src)[q];
            u[q >> 1][(q & 1) * 4 + 0] = (short)f2bf(v.x);
            u[q >> 1][(q & 1) * 4 + 1] = (short)f2bf(v.y);
            u[q >> 1][(q & 1) * 4 + 2] = (short)f2bf(v.z);
            u[q >> 1][(q & 1) * 4 + 3] = (short)f2bf(v.w);
        }
        unsigned short* xb = Xb + (long)(sg + r) * E + c;
        #pragma unroll
        for (int j = 0; j < 4; ++j) {
            *(short8v*)&Xs[r][c + j * 8] = u[j];
            *(short8v*)(xb + j * 8)      = u[j];
        }
    }
    __syncthreads();
    const int w = t >> 6, lane = t & 63, lr = lane & 15, lg = lane >> 4;
    const unsigned short* Bmat = (w < 4) ? P : Rt;
    const int cb = (w & 3) * 64;
    const unsigned short* pb = Bmat + (long)(cb + lr) * E + lg * 8;
    const unsigned short* pa[4];
    #pragma unroll
    for (int mi = 0; mi < 4; ++mi) pa[mi] = &Xs[mi * 16 + lr][lg * 8];
    f32x4 acc[4][4] = {};
    #pragma unroll
    for (int k = 0; k < E; k += 32) {
        short8v a[4];
        #pragma unroll
        for (int mi = 0; mi < 4; ++mi) a[mi] = *(const short8v*)(pa[mi] + k);
        #pragma unroll
        for (int ni = 0; ni < 4; ++ni) {
            const short8v bf = *(const short8v*)(pb + (long)ni * 16 * E + k);
            #pragma unroll
            for (int mi = 0; mi < 4; ++mi)
                acc[mi][ni] = mfma16(a[mi], bf, acc[mi][ni]);
        }
    }
    __syncthreads();                           // Xs dead; reuse as Tt
    const int crow = (w < 4 ? cb : 256 + cb);
    #pragma unroll
    for (int mi = 0; mi < 4; ++mi)
        #pragma unroll
        for (int ni = 0; ni < 4; ++ni)
            #pragma unroll
            for (int r = 0; r < 4; ++r)
                Tt[crow + ni * 16 + lr][mi * 16 + lg * 4 + r] = f2bf(acc[mi][ni][r]);
    __syncthreads();
    {   // write-out: thread t owns transposed row t (Y: 0..255, Z: 256..511)
        unsigned short* dst = (t < 256)
            ? (YT + ((long)(b * E + t)) * S + (sg & 4095))
            : (ZT + ((long)(b * E + (t - 256))) * S + (sg & 4095));
        #pragma unroll
        for (int q = 0; q < 8; ++q)
            *(short8v*)(dst + q * 8) = *(const short8v*)&Tt[t][q * 8];
    }
}

// ---------------------------------------------------------------------------
// K3: MT[b][g][e] = 1e-11 * sum_s ZT[b][g][s] * YT[b][e][s].
// 256 blocks x 512 thr; 8-way split-K + LDS reduce; XCD-chunk swizzle.
__global__ __launch_bounds__(512) void mt_kernel(
    const unsigned short* __restrict__ ZT, const unsigned short* __restrict__ YT,
    unsigned short* __restrict__ MT)
{
    __shared__ float red[8][64][17];
    const int tile = (blockIdx.x & 7) * 32 + (blockIdx.x >> 3);   // bijective, 256
    const int b  = tile >> 6;
    const int tj = (tile >> 3) & 7;
    const int ti = tile & 7;
    const int wv   = threadIdx.x >> 6;
    const int lane = threadIdx.x & 63;
    const int lr = lane & 15, lg = lane >> 4;
    const unsigned short* Abase = ZT + (long)b * E * S + wv * 512 + lg * 8;
    const unsigned short* Bbase = YT + (long)b * E * S + wv * 512 + lg * 8;
    f32x4 acc[4] = {};
    gemm_tile32(Abase + (long)(ti * 32 + lr) * S,
                Bbase + (long)(tj * 32 + lr) * S, S, S, 512, acc);
    #pragma unroll
    for (int q = 0; q < 4; ++q)
        #pragma unroll
        for (int r = 0; r < 4; ++r)
            red[wv][lane][q * 4 + r] = acc[q][r];
    __syncthreads();
    const int lane2 = threadIdx.x & 63;
    const int ib    = threadIdx.x >> 6;
    unsigned short* outg = MT + ((long)b << 16);
    #pragma unroll
    for (int h = 0; h < 2; ++h) {
        const int idx = ib + h * 8;
        float s = 0.f;
        #pragma unroll
        for (int c = 0; c < 8; ++c) s += red[c][lane2][idx];
        const int q = idx >> 2, r = idx & 3;
        const int row = ti * 32 + (q >> 1) * 16 + (lane2 >> 4) * 4 + r;   // g
        const int col = tj * 32 + (q & 1) * 16 + (lane2 & 15);            // e
        outg[row * E + col] = f2bf(s * 1e-11f);
    }
}

// ---------------------------------------------------------------------------
// K4: out = Xb @ M_b (bf16 Xb written by yz).
// Block = 32 s-rows; 4 waves share A rows, each wave owns one 64-wide g-tile.
__global__ __launch_bounds__(256) void final_kernel(
    const unsigned short* __restrict__ Xb, const unsigned short* __restrict__ MT,
    float* __restrict__ Out)
{
    const int s0 = blockIdx.x * 32;
    const int b  = s0 >> 12;
    const int w  = threadIdx.x >> 6;
    const int g0 = w * 64;
    const int lane = threadIdx.x & 63;
    const int lr = lane & 15, lg = lane >> 4;
    const unsigned short* pa0 = Xb + (long)(s0 + lr) * E + lg * 8;
    const unsigned short* pa1 = pa0 + 16 * E;
    const unsigned short* pb  = MT + ((long)b * E + g0 + lr) * E + lg * 8;
    f32x4 acc[2][4] = {};
    #pragma unroll
    for (int k = 0; k < E; k += 32) {
        const short8v a0 = *(const short8v*)(pa0 + k);
        const short8v a1 = *(const short8v*)(pa1 + k);
        #pragma unroll
        for (int ni = 0; ni < 4; ++ni) {
            const short8v bf = *(const short8v*)(pb + (long)ni * 16 * E + k);
            acc[0][ni] = mfma16(a0, bf, acc[0][ni]);
            acc[1][ni] = mfma16(a1, bf, acc[1][ni]);
        }
    }
    #pragma unroll
    for (int mi = 0; mi < 2; ++mi)
        #pragma unroll
        for (int r = 0; r < 4; ++r) {
            float* row = Out + (long)(s0 + mi * 16 + lg * 4 + r) * E + g0 + lr;
            #pragma unroll
            for (int ni = 0; ni < 4; ++ni) row[ni * 16] = acc[mi][ni][r];
        }
}

// ---------------------------------------------------------------------------
extern "C" void kernel_launch(void* const* d_in, const int* in_sizes, int n_in,
                              void* d_out, int out_size, void* d_ws, size_t ws_size,
                              hipStream_t stream)
{
    const float* x  = (const float*)d_in[0];
    const float* Wq = (const float*)d_in[1];
    const float* Wk = (const float*)d_in[2];
    const float* Wv = (const float*)d_in[3];
    const float* Wo = (const float*)d_in[4];
    float* out = (float*)d_out;

    char* ws = (char*)d_ws;
    unsigned short* YT = (unsigned short*)(ws);                   //  8.39 MB
    unsigned short* ZT = (unsigned short*)(ws + 8388608);         //  8.39 MB
    unsigned short* Xb = (unsigned short*)(ws + 16777216);        //  8.39 MB
    unsigned short* P  = (unsigned short*)(ws + 25165824);        //  0.13 MB
    unsigned short* Rt = (unsigned short*)(ws + 25296896);        //  0.13 MB
    unsigned short* MT = (unsigned short*)(ws + 25427968);        //  0.52 MB (ends ~26 MB)

    pr_kernel   <<<dim3(32),  dim3(256), 0, stream>>>(Wq, Wk, Wv, Wo, P, Rt);
    yz_kernel   <<<dim3(256), dim3(512), 0, stream>>>(x, P, Rt, YT, ZT, Xb);
    mt_kernel   <<<dim3(256), dim3(512), 0, stream>>>(ZT, YT, MT);
    final_kernel<<<dim3(512), dim3(256), 0, stream>>>(Xb, MT, out);
}

// Round 16
// 64.669 us; speedup vs baseline: 1.3213x; 1.0047x over previous
//
#include <hip/hip_runtime.h>

static constexpr int E = 256;
static constexpr int S = 4096;

typedef __attribute__((ext_vector_type(8))) short short8v;   // 8 bf16 (4 VGPRs)
typedef __attribute__((ext_vector_type(4))) float f32x4;     // 4 fp32 acc

static __device__ __forceinline__ unsigned short f2bf(float f) {
    union { float f; unsigned u; } v; v.f = f;
    unsigned r = v.u + 0x7fffu + ((v.u >> 16) & 1u);   // RNE
    return (unsigned short)(r >> 16);
}

static __device__ __forceinline__ f32x4 mfma16(short8v a, short8v b, f32x4 c) {
    return __builtin_amdgcn_mfma_f32_16x16x32_bf16(a, b, c, 0, 0, 0);
}

// 32x32 output tile, 1 wave. out[row,col] = sum_k A[row,k]*B[col,k] (both row-major).
static __device__ __forceinline__ void gemm_tile32(
    const unsigned short* pa0, const unsigned short* pb0,
    long sA, long sB, int K, f32x4 acc[4])
{
    const unsigned short* pa1 = pa0 + 16 * sA;
    const unsigned short* pb1 = pb0 + 16 * sB;
    #pragma unroll 4
    for (int k = 0; k < K; k += 32) {
        const short8v a0 = *(const short8v*)(pa0 + k);
        const short8v a1 = *(const short8v*)(pa1 + k);
        const short8v b0 = *(const short8v*)(pb0 + k);
        const short8v b1 = *(const short8v*)(pb1 + k);
        acc[0] = mfma16(a0, b0, acc[0]);
        acc[1] = mfma16(a0, b1, acc[1]);
        acc[2] = mfma16(a1, b0, acc[2]);
        acc[3] = mfma16(a1, b1, acc[3]);
    }
}

// ---------------------------------------------------------------------------
// K1: P = Wq^T Wk (blocks 0..15), Rt = Wo Wv (blocks 16..31). 256 thr.
__global__ __launch_bounds__(256) void pr_kernel(
    const float* __restrict__ Wq, const float* __restrict__ Wk,
    const float* __restrict__ Wv, const float* __restrict__ Wo,
    unsigned short* __restrict__ P, unsigned short* __restrict__ Rt)
{
    __shared__ unsigned short PA[64][264];
    __shared__ unsigned short PB[64][264];
    const int bid  = blockIdx.x;
    const int mode = bid >> 4;                 // 0: P, 1: Rt
    const int tile = bid & 15;
    const int I0 = (tile >> 2) * 64, J0 = (tile & 3) * 64;
    const int t = threadIdx.x;
    {   // PB always transposed: PB[j][g] = (mode? Wv : Wk)[g][J0+j]
        const float* row = (mode ? Wv : Wk) + (long)t * E + J0;
        #pragma unroll
        for (int q = 0; q < 16; ++q) {
            const float4 v = ((const float4*)row)[q];
            PB[q*4+0][t] = f2bf(v.x); PB[q*4+1][t] = f2bf(v.y);
            PB[q*4+2][t] = f2bf(v.z); PB[q*4+3][t] = f2bf(v.w);
        }
    }
    if (mode == 0) {                           // PA[i][g] = Wq[g][I0+i]
        const float* row = Wq + (long)t * E + I0;
        #pragma unroll
        for (int q = 0; q < 16; ++q) {
            const float4 v = ((const float4*)row)[q];
            PA[q*4+0][t] = f2bf(v.x); PA[q*4+1][t] = f2bf(v.y);
            PA[q*4+2][t] = f2bf(v.z); PA[q*4+3][t] = f2bf(v.w);
        }
    } else {                                   // PA[r][f] = Wo[I0+r][f]
        const int r = t >> 2, seg = (t & 3) * 64;
        const float* row = Wo + (long)(I0 + r) * E + seg;
        #pragma unroll
        for (int q = 0; q < 16; ++q) {
            const float4 v = ((const float4*)row)[q];
            PA[r][seg + q*4 + 0] = f2bf(v.x); PA[r][seg + q*4 + 1] = f2bf(v.y);
            PA[r][seg + q*4 + 2] = f2bf(v.z); PA[r][seg + q*4 + 3] = f2bf(v.w);
        }
    }
    __syncthreads();
    const int w = t >> 6, lane = t & 63, lr = lane & 15, lg = lane >> 4;
    f32x4 acc[4] = {};
    gemm_tile32(&PA[(w >> 1) * 32 + lr][lg * 8],
                &PB[(w & 1) * 32 + lr][lg * 8], 264, 264, 256, acc);
    unsigned short* out = mode ? Rt : P;
    #pragma unroll
    for (int q = 0; q < 4; ++q) {
        const int qr = q >> 1, qc = q & 1;
        #pragma unroll
        for (int r = 0; r < 4; ++r)
            out[(I0 + (w >> 1) * 32 + qr * 16 + lg * 4 + r) * E
                + J0 + (w & 1) * 32 + qc * 16 + lr] = f2bf(acc[q][r]);
    }
}

// ---------------------------------------------------------------------------
// K2: Y = Xb @ P^T, Z = Xb @ R~. 256 blocks x 512 thr, 64 s-rows per block.
// Stage 64 x-rows fp32->bf16 in LDS (+spill to Xb); 8 waves: w<4 -> Y cols
// w*64.., w>=4 -> Z cols. Each wave: 64x64 output (acc[4][4]).
// Epilogue: LDS transpose -> YT[b][e'][s], ZT[b][g][s].
__global__ __launch_bounds__(512) void yz_kernel(
    const float* __restrict__ X, const unsigned short* __restrict__ P,
    const unsigned short* __restrict__ Rt,
    unsigned short* __restrict__ YT, unsigned short* __restrict__ ZT,
    unsigned short* __restrict__ Xb)
{
    __shared__ unsigned short lds[512 * 72];   // 73.7 KB union: Xs[64][264] / Tt[512][72]
    unsigned short (*Xs)[264] = (unsigned short (*)[264])lds;
    unsigned short (*Tt)[72]  = (unsigned short (*)[72])lds;
    const int sg = blockIdx.x * 64;
    const int b  = sg >> 12;
    const int t  = threadIdx.x;
    {   // stage 64 x-rows as bf16 (8 thr/row, 32 floats each); also spill to Xb
        const int r = t >> 3, c = (t & 7) * 32;
        const float* src = X + (long)(sg + r) * E + c;
        short8v u[4];
        #pragma unroll
        for (int q = 0; q < 8; ++q) {
            const float4 v = ((const float4*)src)[q];
            u[q >> 1][(q & 1) * 4 + 0] = (short)f2bf(v.x);
            u[q >> 1][(q & 1) * 4 + 1] = (short)f2bf(v.y);
            u[q >> 1][(q & 1) * 4 + 2] = (short)f2bf(v.z);
            u[q >> 1][(q & 1) * 4 + 3] = (short)f2bf(v.w);
        }
        unsigned short* xb = Xb + (long)(sg + r) * E + c;
        #pragma unroll
        for (int j = 0; j < 4; ++j) {
            *(short8v*)&Xs[r][c + j * 8] = u[j];
            *(short8v*)(xb + j * 8)      = u[j];
        }
    }
    __syncthreads();
    const int w = t >> 6, lane = t & 63, lr = lane & 15, lg = lane >> 4;
    const unsigned short* Bmat = (w < 4) ? P : Rt;
    const int cb = (w & 3) * 64;
    const unsigned short* pb = Bmat + (long)(cb + lr) * E + lg * 8;
    const unsigned short* pa[4];
    #pragma unroll
    for (int mi = 0; mi < 4; ++mi) pa[mi] = &Xs[mi * 16 + lr][lg * 8];
    f32x4 acc[4][4] = {};
    #pragma unroll
    for (int k = 0; k < E; k += 32) {
        short8v a[4];
        #pragma unroll
        for (int mi = 0; mi < 4; ++mi) a[mi] = *(const short8v*)(pa[mi] + k);
        #pragma unroll
        for (int ni = 0; ni < 4; ++ni) {
            const short8v bf = *(const short8v*)(pb + (long)ni * 16 * E + k);
            #pragma unroll
            for (int mi = 0; mi < 4; ++mi)
                acc[mi][ni] = mfma16(a[mi], bf, acc[mi][ni]);
        }
    }
    __syncthreads();                           // Xs dead; reuse as Tt
    const int crow = (w < 4 ? cb : 256 + cb);
    #pragma unroll
    for (int mi = 0; mi < 4; ++mi)
        #pragma unroll
        for (int ni = 0; ni < 4; ++ni)
            #pragma unroll
            for (int r = 0; r < 4; ++r)
                Tt[crow + ni * 16 + lr][mi * 16 + lg * 4 + r] = f2bf(acc[mi][ni][r]);
    __syncthreads();
    {   // write-out: thread t owns transposed row t (Y: 0..255, Z: 256..511)
        unsigned short* dst = (t < 256)
            ? (YT + ((long)(b * E + t)) * S + (sg & 4095))
            : (ZT + ((long)(b * E + (t - 256))) * S + (sg & 4095));
        #pragma unroll
        for (int q = 0; q < 8; ++q)
            *(short8v*)(dst + q * 8) = *(const short8v*)&Tt[t][q * 8];
    }
}

// ---------------------------------------------------------------------------
// K3: MT[b][g][e] = 1e-11 * sum_s ZT[b][g][s] * YT[b][e][s].
// 256 blocks x 512 thr; 8-way split-K + LDS reduce; XCD-chunk swizzle.
__global__ __launch_bounds__(512) void mt_kernel(
    const unsigned short* __restrict__ ZT, const unsigned short* __restrict__ YT,
    unsigned short* __restrict__ MT)
{
    __shared__ float red[8][64][17];
    const int tile = (blockIdx.x & 7) * 32 + (blockIdx.x >> 3);   // bijective, 256
    const int b  = tile >> 6;
    const int tj = (tile >> 3) & 7;
    const int ti = tile & 7;
    const int wv   = threadIdx.x >> 6;
    const int lane = threadIdx.x & 63;
    const int lr = lane & 15, lg = lane >> 4;
    const unsigned short* Abase = ZT + (long)b * E * S + wv * 512 + lg * 8;
    const unsigned short* Bbase = YT + (long)b * E * S + wv * 512 + lg * 8;
    f32x4 acc[4] = {};
    gemm_tile32(Abase + (long)(ti * 32 + lr) * S,
                Bbase + (long)(tj * 32 + lr) * S, S, S, 512, acc);
    #pragma unroll
    for (int q = 0; q < 4; ++q)
        #pragma unroll
        for (int r = 0; r < 4; ++r)
            red[wv][lane][q * 4 + r] = acc[q][r];
    __syncthreads();
    const int lane2 = threadIdx.x & 63;
    const int ib    = threadIdx.x >> 6;
    unsigned short* outg = MT + ((long)b << 16);
    #pragma unroll
    for (int h = 0; h < 2; ++h) {
        const int idx = ib + h * 8;
        float s = 0.f;
        #pragma unroll
        for (int c = 0; c < 8; ++c) s += red[c][lane2][idx];
        const int q = idx >> 2, r = idx & 3;
        const int row = ti * 32 + (q >> 1) * 16 + (lane2 >> 4) * 4 + r;   // g
        const int col = tj * 32 + (q & 1) * 16 + (lane2 & 15);            // e
        outg[row * E + col] = f2bf(s * 1e-11f);
    }
}

// ---------------------------------------------------------------------------
// K4: out = Xb @ M_b. 256 blocks x 512 thr, 64 s-rows per block.
// 8 waves = 2 s-groups x 4 g-slices; per-wave code identical to R15
// (bit-identical output), MT L2 traffic halved.
__global__ __launch_bounds__(512) void final_kernel(
    const unsigned short* __restrict__ Xb, const unsigned short* __restrict__ MT,
    float* __restrict__ Out)
{
    const int sg = blockIdx.x * 64;
    const int b  = sg >> 12;
    const int w  = threadIdx.x >> 6;
    const int s0 = sg + (w >> 2) * 32;
    const int g0 = (w & 3) * 64;
    const int lane = threadIdx.x & 63;
    const int lr = lane & 15, lg = lane >> 4;
    const unsigned short* pa0 = Xb + (long)(s0 + lr) * E + lg * 8;
    const unsigned short* pa1 = pa0 + 16 * E;
    const unsigned short* pb  = MT + ((long)b * E + g0 + lr) * E + lg * 8;
    f32x4 acc[2][4] = {};
    #pragma unroll
    for (int k = 0; k < E; k += 32) {
        const short8v a0 = *(const short8v*)(pa0 + k);
        const short8v a1 = *(const short8v*)(pa1 + k);
        #pragma unroll
        for (int ni = 0; ni < 4; ++ni) {
            const short8v bf = *(const short8v*)(pb + (long)ni * 16 * E + k);
            acc[0][ni] = mfma16(a0, bf, acc[0][ni]);
            acc[1][ni] = mfma16(a1, bf, acc[1][ni]);
        }
    }
    #pragma unroll
    for (int mi = 0; mi < 2; ++mi)
        #pragma unroll
        for (int r = 0; r < 4; ++r) {
            float* row = Out + (long)(s0 + mi * 16 + lg * 4 + r) * E + g0 + lr;
            #pragma unroll
            for (int ni = 0; ni < 4; ++ni) row[ni * 16] = acc[mi][ni][r];
        }
}

// ---------------------------------------------------------------------------
extern "C" void kernel_launch(void* const* d_in, const int* in_sizes, int n_in,
                              void* d_out, int out_size, void* d_ws, size_t ws_size,
                              hipStream_t stream)
{
    const float* x  = (const float*)d_in[0];
    const float* Wq = (const float*)d_in[1];
    const float* Wk = (const float*)d_in[2];
    const float* Wv = (const float*)d_in[3];
    const float* Wo = (const float*)d_in[4];
    float* out = (float*)d_out;

    char* ws = (char*)d_ws;
    unsigned short* YT = (unsigned short*)(ws);                   //  8.39 MB
    unsigned short* ZT = (unsigned short*)(ws + 8388608);         //  8.39 MB
    unsigned short* Xb = (unsigned short*)(ws + 16777216);        //  8.39 MB
    unsigned short* P  = (unsigned short*)(ws + 25165824);        //  0.13 MB
    unsigned short* Rt = (unsigned short*)(ws + 25296896);        //  0.13 MB
    unsigned short* MT = (unsigned short*)(ws + 25427968);        //  0.52 MB (ends ~26 MB)

    pr_kernel   <<<dim3(32),  dim3(256), 0, stream>>>(Wq, Wk, Wv, Wo, P, Rt);
    yz_kernel   <<<dim3(256), dim3(512), 0, stream>>>(x, P, Rt, YT, ZT, Xb);
    mt_kernel   <<<dim3(256), dim3(512), 0, stream>>>(ZT, YT, MT);
    final_kernel<<<dim3(256), dim3(512), 0, stream>>>(Xb, MT, out);
}